// Round 3
// baseline (358.843 us; speedup 1.0000x reference)
//
#include <hip/hip_runtime.h>

#define NSUB  2500   // C(16,2)+C(16,3)+C(16,4) = 120+560+1820
#define NCOL  2516   // 16 + NSUB
#define NROW  16
#define NQUAD 625    // NSUB / 4
#define NPAIR 120

// LDS word layout: [0..15] = t_j, [16] = 0.0 pad, [17..136] = pair sums.
// Every subset sum = lds[a] + lds[b] with precomputed u8 word indices:
//   size-2 (i,j):     a = 17+pidx(i,j), b = 16 (zero)
//   size-3 (i,j,k):   a = 17+pidx(i,j), b = k
//   size-4 (i,j,k,l): a = 17+pidx(i,j), b = 17+pidx(k,l)
struct SubTable { unsigned char idx[NSUB][2]; };
struct PairTable { unsigned char pr[NPAIR][2]; };

constexpr SubTable make_table() {
    SubTable tb{};
    int pidx[16][16] = {};
    {
        int p = 0;
        for (int i = 0; i < 16; ++i)
            for (int j = i + 1; j < 16; ++j) pidx[i][j] = p++;
    }
    int s = 0;
    for (int i = 0; i < 16; ++i)
        for (int j = i + 1; j < 16; ++j) {
            tb.idx[s][0] = (unsigned char)(17 + pidx[i][j]);
            tb.idx[s][1] = 16;  ++s;
        }
    for (int i = 0; i < 16; ++i)
        for (int j = i + 1; j < 16; ++j)
            for (int k = j + 1; k < 16; ++k) {
                tb.idx[s][0] = (unsigned char)(17 + pidx[i][j]);
                tb.idx[s][1] = (unsigned char)k;  ++s;
            }
    for (int i = 0; i < 16; ++i)
        for (int j = i + 1; j < 16; ++j)
            for (int k = j + 1; k < 16; ++k)
                for (int l = k + 1; l < 16; ++l) {
                    tb.idx[s][0] = (unsigned char)(17 + pidx[i][j]);
                    tb.idx[s][1] = (unsigned char)(17 + pidx[k][l]);  ++s;
                }
    return tb;
}

constexpr PairTable make_pairs() {
    PairTable t{};
    int p = 0;
    for (int i = 0; i < 16; ++i)
        for (int j = i + 1; j < 16; ++j) {
            t.pr[p][0] = (unsigned char)i;
            t.pr[p][1] = (unsigned char)j;  ++p;
        }
    return t;
}

__constant__ SubTable  g_tab = make_table();
__constant__ PairTable g_pr  = make_pairs();

typedef float         f32x4 __attribute__((ext_vector_type(4)));
typedef unsigned char u8x8  __attribute__((ext_vector_type(8)));

// h = 1/(1 + s^(1/lam)) via raw HW transcendentals (s in ~[0.8,10], no edge cases)
__device__ __forceinline__ float hval(float s, float p) {
    float q = __builtin_amdgcn_logf(s);        // log2(s)
    float e = __builtin_amdgcn_exp2f(p * q);   // s^p
    return __builtin_amdgcn_rcpf(1.0f + e);
}

__global__ __launch_bounds__(256) void dombi_kernel(const float* __restrict__ x,
                                                    const float* __restrict__ lam_p,
                                                    float* __restrict__ out) {
    __shared__ float tt[137];   // t[17] + pairsum[120]
    const int   row     = blockIdx.x;
    const int   tid     = threadIdx.x;
    const float lam     = lam_p[0];
    const float inv_lam = 1.0f / lam;

    const float* xr   = x   + (size_t)row * NROW;
    float*       orow = out + (size_t)row * NCOL;

    if (tid < NROW) {
        float xv = xr[tid];
        tt[tid] = powf(1.0f / xv - 1.0f, lam);  // accurate: only 16/row
    } else if (tid == NROW) {
        tt[NROW] = 0.0f;                        // zero pad slot
    }
    if (tid < 4) {                              // pass-through cols 0..15
        reinterpret_cast<f32x4*>(orow)[tid] =
            reinterpret_cast<const f32x4*>(xr)[tid];
    }
    __syncthreads();

    if (tid < NPAIR) {                          // build the 120 pair sums
        tt[17 + tid] = tt[g_pr.pr[tid][0]] + tt[g_pr.pr[tid][1]];
    }
    __syncthreads();

    const u8x8* cp = reinterpret_cast<const u8x8*>(&g_tab.idx[0][0]);
    f32x4*      o4 = reinterpret_cast<f32x4*>(orow + NROW);   // 16B-aligned

    for (int s4 = tid; s4 < NQUAD; s4 += 256) {
        u8x8 c = cp[s4];                        // 4 subsets, 2 LDS indices each
        f32x4 r;
        r.x = hval(tt[c[0]] + tt[c[1]], inv_lam);
        r.y = hval(tt[c[2]] + tt[c[3]], inv_lam);
        r.z = hval(tt[c[4]] + tt[c[5]], inv_lam);
        r.w = hval(tt[c[6]] + tt[c[7]], inv_lam);
        __builtin_nontemporal_store(r, &o4[s4]);
    }
}

extern "C" void kernel_launch(void* const* d_in, const int* in_sizes, int n_in,
                              void* d_out, int out_size, void* d_ws, size_t ws_size,
                              hipStream_t stream) {
    const float* x   = (const float*)d_in[0];
    const float* lam = (const float*)d_in[1];
    float*       out = (float*)d_out;
    const int B = in_sizes[0] / NROW;   // 32768
    dombi_kernel<<<B, 256, 0, stream>>>(x, lam, out);
}

// Round 7
// 357.670 us; speedup vs baseline: 1.0033x; 1.0033x over previous
//
#include <hip/hip_runtime.h>

#define NSUB  2500   // C(16,2)+C(16,3)+C(16,4) = 120+560+1820
#define NCOL  2516   // 16 + NSUB
#define NROW  16
#define NQUAD 625    // NSUB / 4
#define NPAIR 120
#define RPB   8      // rows per block (2 per wave)
#define TSTR  137    // tt row stride in words: t[17] + pairsum[120]

// LDS word layout per row: [0..15]=t_j, [16]=0.0 pad, [17..136]=pair sums.
// Every subset sum = tt[a] + tt[b], u8 indices precomputed per subset.
struct SubTable  { unsigned char idx[NSUB][2]; };
struct PairTable { unsigned char pr[NPAIR][2]; };

constexpr SubTable make_table() {
    SubTable tb{};
    int pidx[16][16] = {};
    {
        int p = 0;
        for (int i = 0; i < 16; ++i)
            for (int j = i + 1; j < 16; ++j) pidx[i][j] = p++;
    }
    int s = 0;
    for (int i = 0; i < 16; ++i)
        for (int j = i + 1; j < 16; ++j) {
            tb.idx[s][0] = (unsigned char)(17 + pidx[i][j]);
            tb.idx[s][1] = 16;  ++s;
        }
    for (int i = 0; i < 16; ++i)
        for (int j = i + 1; j < 16; ++j)
            for (int k = j + 1; k < 16; ++k) {
                tb.idx[s][0] = (unsigned char)(17 + pidx[i][j]);
                tb.idx[s][1] = (unsigned char)k;  ++s;
            }
    for (int i = 0; i < 16; ++i)
        for (int j = i + 1; j < 16; ++j)
            for (int k = j + 1; k < 16; ++k)
                for (int l = k + 1; l < 16; ++l) {
                    tb.idx[s][0] = (unsigned char)(17 + pidx[i][j]);
                    tb.idx[s][1] = (unsigned char)(17 + pidx[k][l]);  ++s;
                }
    return tb;
}

constexpr PairTable make_pairs() {
    PairTable t{};
    int p = 0;
    for (int i = 0; i < 16; ++i)
        for (int j = i + 1; j < 16; ++j) {
            t.pr[p][0] = (unsigned char)i;
            t.pr[p][1] = (unsigned char)j;  ++p;
        }
    return t;
}

__constant__ SubTable  g_tab = make_table();
__constant__ PairTable g_pr  = make_pairs();

typedef float         f32x4 __attribute__((ext_vector_type(4)));
typedef unsigned char u8x8  __attribute__((ext_vector_type(8)));

// h = 1/(1 + s^(1/lam)) via raw HW transcendentals (s in ~[0.8,10], no edge cases)
__device__ __forceinline__ float hval(float s, float p) {
    float q = __builtin_amdgcn_logf(s);        // log2(s)
    float e = __builtin_amdgcn_exp2f(p * q);   // s^p
    return __builtin_amdgcn_rcpf(1.0f + e);
}

// 8 rows per block, 2 rows per wave. Coalesced 512B input load, single
// prologue barrier pair, then a fully-unrolled 10-iter hot loop per wave
// (table indices shared across its 2 rows, f32x4 NT stores).
__global__ __launch_bounds__(256, 4) void dombi_kernel(const float* __restrict__ x,
                                                       const float* __restrict__ lam_p,
                                                       float* __restrict__ out) {
    __shared__ float tt[RPB][TSTR];
    const int   tid     = threadIdx.x;
    const int   row0    = blockIdx.x * RPB;
    const float lam     = lam_p[0];
    const float inv_lam = 1.0f / lam;

    const float* xb = x + (size_t)row0 * NROW;       // 128 consecutive floats

    if (tid < RPB * NROW) {                          // coalesced input load
        float xv = xb[tid];
        int r = tid >> 4, j = tid & 15;
        out[(size_t)(row0 + r) * NCOL + j] = xv;     // pass-through cols
        tt[r][j] = powf(1.0f / xv - 1.0f, lam);      // accurate: 128/block
        if (j == 0) tt[r][16] = 0.0f;                // zero pad slot
    }
    __syncthreads();

    for (int k = tid; k < RPB * NPAIR; k += 256) {   // 960 pair sums
        int r = k / NPAIR;
        int p = k - r * NPAIR;
        tt[r][17 + p] = tt[r][g_pr.pr[p][0]] + tt[r][g_pr.pr[p][1]];
    }
    __syncthreads();

    const int wave = tid >> 6;
    const int lane = tid & 63;
    const int rA   = wave * 2;
    const int rB   = rA + 1;
    const u8x8* cp = reinterpret_cast<const u8x8*>(&g_tab.idx[0][0]);
    f32x4* oA = reinterpret_cast<f32x4*>(out + (size_t)(row0 + rA) * NCOL + NROW);
    f32x4* oB = reinterpret_cast<f32x4*>(out + (size_t)(row0 + rB) * NCOL + NROW);

#pragma unroll
    for (int it = 0; it < 10; ++it) {
        const int  q   = it * 64 + lane;             // quad index in [0,625)
        const bool act = (q < NQUAD);
        const int  qc  = act ? q : NQUAD - 1;
        u8x8 c = cp[qc];                             // 4 subsets × 2 indices
        f32x4 vA, vB;
        vA.x = hval(tt[rA][c[0]] + tt[rA][c[1]], inv_lam);
        vA.y = hval(tt[rA][c[2]] + tt[rA][c[3]], inv_lam);
        vA.z = hval(tt[rA][c[4]] + tt[rA][c[5]], inv_lam);
        vA.w = hval(tt[rA][c[6]] + tt[rA][c[7]], inv_lam);
        vB.x = hval(tt[rB][c[0]] + tt[rB][c[1]], inv_lam);
        vB.y = hval(tt[rB][c[2]] + tt[rB][c[3]], inv_lam);
        vB.z = hval(tt[rB][c[4]] + tt[rB][c[5]], inv_lam);
        vB.w = hval(tt[rB][c[6]] + tt[rB][c[7]], inv_lam);
        if (act) {
            __builtin_nontemporal_store(vA, &oA[q]);
            __builtin_nontemporal_store(vB, &oB[q]);
        }
    }
}

extern "C" void kernel_launch(void* const* d_in, const int* in_sizes, int n_in,
                              void* d_out, int out_size, void* d_ws, size_t ws_size,
                              hipStream_t stream) {
    const float* x   = (const float*)d_in[0];
    const float* lam = (const float*)d_in[1];
    float*       out = (float*)d_out;
    const int B = in_sizes[0] / NROW;   // 32768
    dombi_kernel<<<B / RPB, 256, 0, stream>>>(x, lam, out);
}

// Round 11
// 350.108 us; speedup vs baseline: 1.0250x; 1.0216x over previous
//
#include <hip/hip_runtime.h>

#define NSUB  2500   // C(16,2)+C(16,3)+C(16,4) = 120+560+1820
#define NCOL  2516   // 16 + NSUB
#define NROW  16
#define NQUAD 625    // NSUB / 4
#define NPAIR 120
#define RPB   8      // rows per block (2 per wave)
#define TSTR  137    // tt row stride in words: t[17] + pairsum[120]

// LDS word layout per row: [0..15]=t_j, [16]=0.0 pad, [17..136]=pair sums.
// Every subset sum = tt[a] + tt[b], u8 indices precomputed per subset.
struct SubTable  { unsigned char idx[NSUB][2]; };
struct PairTable { unsigned char pr[NPAIR][2]; };

constexpr SubTable make_table() {
    SubTable tb{};
    int pidx[16][16] = {};
    {
        int p = 0;
        for (int i = 0; i < 16; ++i)
            for (int j = i + 1; j < 16; ++j) pidx[i][j] = p++;
    }
    int s = 0;
    for (int i = 0; i < 16; ++i)
        for (int j = i + 1; j < 16; ++j) {
            tb.idx[s][0] = (unsigned char)(17 + pidx[i][j]);
            tb.idx[s][1] = 16;  ++s;
        }
    for (int i = 0; i < 16; ++i)
        for (int j = i + 1; j < 16; ++j)
            for (int k = j + 1; k < 16; ++k) {
                tb.idx[s][0] = (unsigned char)(17 + pidx[i][j]);
                tb.idx[s][1] = (unsigned char)k;  ++s;
            }
    for (int i = 0; i < 16; ++i)
        for (int j = i + 1; j < 16; ++j)
            for (int k = j + 1; k < 16; ++k)
                for (int l = k + 1; l < 16; ++l) {
                    tb.idx[s][0] = (unsigned char)(17 + pidx[i][j]);
                    tb.idx[s][1] = (unsigned char)(17 + pidx[k][l]);  ++s;
                }
    return tb;
}

constexpr PairTable make_pairs() {
    PairTable t{};
    int p = 0;
    for (int i = 0; i < 16; ++i)
        for (int j = i + 1; j < 16; ++j) {
            t.pr[p][0] = (unsigned char)i;
            t.pr[p][1] = (unsigned char)j;  ++p;
        }
    return t;
}

__constant__ SubTable  g_tab = make_table();
__constant__ PairTable g_pr  = make_pairs();

typedef float         f32x4 __attribute__((ext_vector_type(4)));
typedef unsigned char u8x8  __attribute__((ext_vector_type(8)));

// h = 1/(1 + s^(1/lam)) via raw HW transcendentals (s in ~[0.8,10], no edge cases)
__device__ __forceinline__ float hval(float s, float p) {
    float q = __builtin_amdgcn_logf(s);        // log2(s)
    float e = __builtin_amdgcn_exp2f(p * q);   // s^p
    return __builtin_amdgcn_rcpf(1.0f + e);
}

// 8 rows per block, 2 rows per wave. Identical to round-7 kernel EXCEPT the
// output stores are plain (L2 write path) instead of nontemporal — A/B test:
// the harness fill streams 6+ TB/s with plain stores; our NT stores measured
// ~2.3 TB/s effective.
__global__ __launch_bounds__(256, 4) void dombi_kernel(const float* __restrict__ x,
                                                       const float* __restrict__ lam_p,
                                                       float* __restrict__ out) {
    __shared__ float tt[RPB][TSTR];
    const int   tid     = threadIdx.x;
    const int   row0    = blockIdx.x * RPB;
    const float lam     = lam_p[0];
    const float inv_lam = 1.0f / lam;

    const float* xb = x + (size_t)row0 * NROW;       // 128 consecutive floats

    if (tid < RPB * NROW) {                          // coalesced input load
        float xv = xb[tid];
        int r = tid >> 4, j = tid & 15;
        out[(size_t)(row0 + r) * NCOL + j] = xv;     // pass-through cols
        tt[r][j] = powf(1.0f / xv - 1.0f, lam);      // accurate: 128/block
        if (j == 0) tt[r][16] = 0.0f;                // zero pad slot
    }
    __syncthreads();

    for (int k = tid; k < RPB * NPAIR; k += 256) {   // 960 pair sums
        int r = k / NPAIR;
        int p = k - r * NPAIR;
        tt[r][17 + p] = tt[r][g_pr.pr[p][0]] + tt[r][g_pr.pr[p][1]];
    }
    __syncthreads();

    const int wave = tid >> 6;
    const int lane = tid & 63;
    const int rA   = wave * 2;
    const int rB   = rA + 1;
    const u8x8* cp = reinterpret_cast<const u8x8*>(&g_tab.idx[0][0]);
    f32x4* oA = reinterpret_cast<f32x4*>(out + (size_t)(row0 + rA) * NCOL + NROW);
    f32x4* oB = reinterpret_cast<f32x4*>(out + (size_t)(row0 + rB) * NCOL + NROW);

#pragma unroll
    for (int it = 0; it < 10; ++it) {
        const int  q   = it * 64 + lane;             // quad index in [0,625)
        const bool act = (q < NQUAD);
        const int  qc  = act ? q : NQUAD - 1;
        u8x8 c = cp[qc];                             // 4 subsets × 2 indices
        f32x4 vA, vB;
        vA.x = hval(tt[rA][c[0]] + tt[rA][c[1]], inv_lam);
        vA.y = hval(tt[rA][c[2]] + tt[rA][c[3]], inv_lam);
        vA.z = hval(tt[rA][c[4]] + tt[rA][c[5]], inv_lam);
        vA.w = hval(tt[rA][c[6]] + tt[rA][c[7]], inv_lam);
        vB.x = hval(tt[rB][c[0]] + tt[rB][c[1]], inv_lam);
        vB.y = hval(tt[rB][c[2]] + tt[rB][c[3]], inv_lam);
        vB.z = hval(tt[rB][c[4]] + tt[rB][c[5]], inv_lam);
        vB.w = hval(tt[rB][c[6]] + tt[rB][c[7]], inv_lam);
        if (act) {
            oA[q] = vA;                              // plain stores (A/B vs NT)
            oB[q] = vB;
        }
    }
}

extern "C" void kernel_launch(void* const* d_in, const int* in_sizes, int n_in,
                              void* d_out, int out_size, void* d_ws, size_t ws_size,
                              hipStream_t stream) {
    const float* x   = (const float*)d_in[0];
    const float* lam = (const float*)d_in[1];
    float*       out = (float*)d_out;
    const int B = in_sizes[0] / NROW;   // 32768
    dombi_kernel<<<B / RPB, 256, 0, stream>>>(x, lam, out);
}